// Round 1
// baseline (3211.489 us; speedup 1.0000x reference)
//
#include <hip/hip_runtime.h>
#include <stdint.h>

// ---------------------------------------------------------------------------
// PerceiverResampler on MI355X (gfx950)
// B=32, F=2048, DIM=1024, INNER=1024, H=16, DH=64, Q=64, DEPTH=6, MULT=2
//
// Strategy:
//  - LN-fold: every _ln(x,g,b)@W becomes rownorm(x) @ (diag(g)W) + (b@W).
//    f's row-stats are depth-invariant -> normalize once into fhat (bf16).
//  - Mask compaction: only unmasked rows (per batch) flow through the
//    down-projection / k / v GEMMs and attention (~2x FLOP cut).
//  - bf16 MFMA 16x16x32 GEMM, 128x128 tile, 4 waves, BK=32,
//    global_load_lds(16B) staging, double-buffered LDS (m97 structure).
//  - Flash attention: one block per (b,h), 64 queries, online softmax.
// ---------------------------------------------------------------------------

#define DEV static __device__ __forceinline__

typedef __attribute__((ext_vector_type(8))) short short8;
typedef __attribute__((ext_vector_type(4))) float f32x4;
typedef __attribute__((ext_vector_type(4))) unsigned short ushort4v;
typedef unsigned short ushort_t;

DEV float bf2f(ushort_t u){ union{uint32_t i; float f;} x; x.i = ((uint32_t)u)<<16; return x.f; }
DEV ushort_t f2bf(float f){
  union{float f; uint32_t i;} x; x.f = f;
  uint32_t r = x.i + 0x7fffu + ((x.i>>16)&1u);  // RNE
  return (ushort_t)(r>>16);
}

#define GLOAD16(gp, lp) __builtin_amdgcn_global_load_lds( \
    (const __attribute__((address_space(1))) uint32_t*)(gp), \
    (__attribute__((address_space(3))) uint32_t*)(lp), 16, 0, 0)

// ---------------- block reduce (sum of two values, 256 threads) ------------
DEV void reduce2(float& a, float& b){
  #pragma unroll
  for (int d = 32; d; d >>= 1){ a += __shfl_down(a, d); b += __shfl_down(b, d); }
  __shared__ float sh[8];
  int w = threadIdx.x >> 6, l = threadIdx.x & 63;
  if (l == 0){ sh[w*2] = a; sh[w*2+1] = b; }
  __syncthreads();
  a = sh[0]+sh[2]+sh[4]+sh[6];
  b = sh[1]+sh[3]+sh[5]+sh[7];
}

// ---------------- mask compaction ------------------------------------------
__global__ __launch_bounds__(256) void k_compact(const int* __restrict__ mask,
                                                 int* __restrict__ idx, int* __restrict__ cnt){
  int b = blockIdx.x, t = threadIdx.x;
  const int* mb = mask + b*2048;
  int keep[8]; int c = 0;
  #pragma unroll
  for (int u = 0; u < 8; ++u){ keep[u] = (mb[t*8+u] != 0); c += keep[u]; }
  __shared__ int s[256];
  s[t] = c; __syncthreads();
  for (int off = 1; off < 256; off <<= 1){
    int v = (t >= off) ? s[t-off] : 0;
    __syncthreads();
    s[t] += v;
    __syncthreads();
  }
  int pos = s[t] - c;
  #pragma unroll
  for (int u = 0; u < 8; ++u) if (keep[u]) idx[b*2048 + pos++] = t*8 + u;
  if (t == 255) cnt[b] = s[255];
}

// ---------------- gather + rownorm features -> bf16 ------------------------
__global__ __launch_bounds__(256) void k_gather_norm(const float* __restrict__ feat,
        const int* __restrict__ idx, const int* __restrict__ cnt, ushort_t* __restrict__ outp){
  int blk = blockIdx.x; int b = blk >> 11, j = blk & 2047;
  if (j >= cnt[b]) return;
  int src = idx[b*2048 + j];
  const float* row = feat + ((size_t)(b*2048 + src))*1024;
  int t = threadIdx.x;
  float4 v = *(const float4*)(row + t*4);
  float s = v.x+v.y+v.z+v.w;
  float q = v.x*v.x+v.y*v.y+v.z*v.z+v.w*v.w;
  reduce2(s, q);
  float mean = s * (1.f/1024.f);
  float rstd = rsqrtf(q*(1.f/1024.f) - mean*mean + 1e-5f);
  ushort4v o;
  o.x = f2bf((v.x-mean)*rstd); o.y = f2bf((v.y-mean)*rstd);
  o.z = f2bf((v.z-mean)*rstd); o.w = f2bf((v.w-mean)*rstd);
  *(ushort4v*)(outp + ((size_t)(b*2048+j))*1024 + t*4) = o;
}

// ---------------- rownorm bf16 -> bf16 (optional skip) ---------------------
__global__ __launch_bounds__(256) void k_rownorm_bf16(const ushort_t* __restrict__ in,
        ushort_t* __restrict__ outp, const int* __restrict__ cnt){
  int blk = blockIdx.x;
  if (cnt){ int b = blk >> 11; if ((blk & 2047) >= cnt[b]) return; }
  int t = threadIdx.x;
  ushort4v u = *(const ushort4v*)(in + (size_t)blk*1024 + t*4);
  float f0 = bf2f(u.x), f1 = bf2f(u.y), f2 = bf2f(u.z), f3 = bf2f(u.w);
  float s = f0+f1+f2+f3, q = f0*f0+f1*f1+f2*f2+f3*f3;
  reduce2(s, q);
  float mean = s * (1.f/1024.f);
  float rstd = rsqrtf(q*(1.f/1024.f) - mean*mean + 1e-5f);
  ushort4v o;
  o.x = f2bf((f0-mean)*rstd); o.y = f2bf((f1-mean)*rstd);
  o.z = f2bf((f2-mean)*rstd); o.w = f2bf((f3-mean)*rstd);
  *(ushort4v*)(outp + (size_t)blk*1024 + t*4) = o;
}

// ---------------- rownorm f32 -> bf16 --------------------------------------
__global__ __launch_bounds__(256) void k_rownorm_f32(const float* __restrict__ in,
                                                     ushort_t* __restrict__ outp){
  int blk = blockIdx.x, t = threadIdx.x;
  float4 v = *(const float4*)(in + (size_t)blk*1024 + t*4);
  float s = v.x+v.y+v.z+v.w;
  float q = v.x*v.x+v.y*v.y+v.z*v.z+v.w*v.w;
  reduce2(s, q);
  float mean = s * (1.f/1024.f);
  float rstd = rsqrtf(q*(1.f/1024.f) - mean*mean + 1e-5f);
  ushort4v o;
  o.x = f2bf((v.x-mean)*rstd); o.y = f2bf((v.y-mean)*rstd);
  o.z = f2bf((v.z-mean)*rstd); o.w = f2bf((v.w-mean)*rstd);
  *(ushort4v*)(outp + (size_t)blk*1024 + t*4) = o;
}

// ---------------- final layernorm (affine) f32 -> f32 ----------------------
__global__ __launch_bounds__(256) void k_final_ln(const float* __restrict__ x,
        const float* __restrict__ g, const float* __restrict__ bb, float* __restrict__ outp){
  int blk = blockIdx.x, t = threadIdx.x;
  float4 v = *(const float4*)(x + (size_t)blk*1024 + t*4);
  float s = v.x+v.y+v.z+v.w;
  float q = v.x*v.x+v.y*v.y+v.z*v.z+v.w*v.w;
  reduce2(s, q);
  float mean = s * (1.f/1024.f);
  float rstd = rsqrtf(q*(1.f/1024.f) - mean*mean + 1e-5f);
  float4 gg = *(const float4*)(g + t*4);
  float4 bv = *(const float4*)(bb + t*4);
  float4 o;
  o.x = (v.x-mean)*rstd*gg.x + bv.x; o.y = (v.y-mean)*rstd*gg.y + bv.y;
  o.z = (v.z-mean)*rstd*gg.z + bv.z; o.w = (v.w-mean)*rstd*gg.w + bv.w;
  *(float4*)(outp + (size_t)blk*1024 + t*4) = o;
}

// ---------------- x init: broadcast latents --------------------------------
__global__ __launch_bounds__(256) void k_init_x(const float* __restrict__ lat, float* __restrict__ x){
  int v = blockIdx.x*256 + threadIdx.x;       // vec4 index, 2048*256 total
  int row = v >> 8, cv = v & 255;
  ((float4*)x)[v] = ((const float4*)lat)[(row & 63)*256 + cv];
}

// ---------------- weight fold + transpose: Wt[n][k] = g[k]*scale*W[k][n] ---
__global__ __launch_bounds__(256) void k_foldT(const float* __restrict__ W,
        const float* __restrict__ g, float scale, ushort_t* __restrict__ Wt, int K, int N){
  int n0 = blockIdx.x*64, k0 = blockIdx.y*64;
  __shared__ float Ts[64][65];
  int t = threadIdx.x;
  #pragma unroll
  for (int i = 0; i < 4; ++i){
    int flat = i*1024 + t*4; int r = flat >> 6, c = flat & 63;
    float4 v = *(const float4*)(W + (size_t)(k0+r)*N + n0 + c);
    float gg = (g ? g[k0+r] : 1.f) * scale;
    Ts[r][c] = v.x*gg; Ts[r][c+1] = v.y*gg; Ts[r][c+2] = v.z*gg; Ts[r][c+3] = v.w*gg;
  }
  __syncthreads();
  #pragma unroll
  for (int i = 0; i < 4; ++i){
    int flat = i*1024 + t*4; int rn = flat >> 6, ck = flat & 63;
    ushort4v o;
    o.x = f2bf(Ts[ck][rn]);   o.y = f2bf(Ts[ck+1][rn]);
    o.z = f2bf(Ts[ck+2][rn]); o.w = f2bf(Ts[ck+3][rn]);
    *(ushort4v*)(Wt + (size_t)(n0+rn)*K + k0 + ck) = o;
  }
}

// ---------------- bias fold: bias[o] = scale * sum_c bvec[c]*W[c][o] -------
__global__ __launch_bounds__(256) void k_foldBias(const float* __restrict__ W,
        const float* __restrict__ bvec, float scale, float* __restrict__ bias, int K, int N){
  int t = threadIdx.x;
  int ol = t & 31, kc = t >> 5;
  int o = blockIdx.x*32 + ol;
  int chunk = K >> 3;
  int c0 = kc*chunk, c1 = c0 + chunk;
  float s0 = 0, s1 = 0, s2 = 0, s3 = 0;
  for (int c = c0; c < c1; c += 4){
    s0 += bvec[c+0]*W[(size_t)(c+0)*N + o];
    s1 += bvec[c+1]*W[(size_t)(c+1)*N + o];
    s2 += bvec[c+2]*W[(size_t)(c+2)*N + o];
    s3 += bvec[c+3]*W[(size_t)(c+3)*N + o];
  }
  __shared__ float red[8][32];
  red[kc][ol] = (s0+s1)+(s2+s3);
  __syncthreads();
  if (kc == 0){
    float tot = 0;
    #pragma unroll
    for (int jj = 0; jj < 8; ++jj) tot += red[jj][ol];
    bias[o] = tot * scale;
  }
}

// ---------------- GEMM: C = A(MxK,bf16) * Bt(NxK,bf16)^T + bias ------------
// OUTMODE: 0 = bf16 store, 1 = bf16 relu store, 2 = f32 accumulate (C += v)
template<int OUTMODE, bool SKIP>
__global__ __launch_bounds__(256) void k_gemm(const ushort_t* __restrict__ A,
        const ushort_t* __restrict__ Bt, const float* __restrict__ bias,
        void* __restrict__ Cp, int M, int N, int K, const int* __restrict__ cnt){
  const int n0 = blockIdx.x * 128;
  const int m0 = blockIdx.y * 128;
  if (SKIP){ int b = m0 >> 11; if ((m0 & 2047) >= cnt[b]) return; }
  __shared__ ushort_t sA[2][128*32];
  __shared__ ushort_t sB[2][128*32];
  const int tid = threadIdx.x;
  const int wave = tid >> 6, lane = tid & 63;
  const int lo = lane & 15, hi = lane >> 4;
  const int wr = wave >> 1, wc = wave & 1;

  auto stage = [&](int buf, int k0){
    #pragma unroll
    for (int p = 0; p < 2; ++p){
      int r = p*64 + wave*16 + (lane >> 2);
      int c = lane & 3;
      {
        const ushort_t* gp = A + (size_t)(m0 + r)*K + k0 + c*8;
        char* lp = (char*)(&sA[buf][0]) + p*4096 + wave*1024;
        GLOAD16(gp, lp);
      }
      {
        const ushort_t* gp = Bt + (size_t)(n0 + r)*K + k0 + c*8;
        char* lp = (char*)(&sB[buf][0]) + p*4096 + wave*1024;
        GLOAD16(gp, lp);
      }
    }
  };

  f32x4 acc[4][4] = {};
  stage(0, 0);
  const int nk = K >> 5;
  for (int ks = 0; ks < nk; ++ks){
    __syncthreads();                       // drains vmcnt: buf[ks&1] ready
    if (ks + 1 < nk) stage((ks+1)&1, (ks+1) << 5);
    const int buf = ks & 1;
    short8 af[4], bfr[4];
    #pragma unroll
    for (int mi = 0; mi < 4; ++mi)
      af[mi] = *(const short8*)(&sA[buf][(wr*64 + mi*16 + lo)*32 + hi*8]);
    #pragma unroll
    for (int ni = 0; ni < 4; ++ni)
      bfr[ni] = *(const short8*)(&sB[buf][(wc*64 + ni*16 + lo)*32 + hi*8]);
    #pragma unroll
    for (int mi = 0; mi < 4; ++mi)
      #pragma unroll
      for (int ni = 0; ni < 4; ++ni)
        acc[mi][ni] = __builtin_amdgcn_mfma_f32_16x16x32_bf16(af[mi], bfr[ni], acc[mi][ni], 0, 0, 0);
  }
  #pragma unroll
  for (int ni = 0; ni < 4; ++ni){
    int col = n0 + wc*64 + ni*16 + lo;
    float bv = bias ? bias[col] : 0.f;
    #pragma unroll
    for (int mi = 0; mi < 4; ++mi){
      int rbase = m0 + wr*64 + mi*16 + hi*4;
      #pragma unroll
      for (int rr = 0; rr < 4; ++rr){
        float v = acc[mi][ni][rr] + bv;
        size_t off = (size_t)(rbase + rr)*N + col;
        if (OUTMODE == 0)      ((ushort_t*)Cp)[off] = f2bf(v);
        else if (OUTMODE == 1) ((ushort_t*)Cp)[off] = f2bf(fmaxf(v, 0.f));
        else                   ((float*)Cp)[off] += v;
      }
    }
  }
}

// ---------------- flash attention: one block per (b,h) ---------------------
__global__ __launch_bounds__(256) void k_attn(const ushort_t* __restrict__ qb,
        const ushort_t* __restrict__ kb, const ushort_t* __restrict__ vbuf,
        const int* __restrict__ cnt, ushort_t* __restrict__ outb){
  const int bh = blockIdx.x;
  const int b = bh >> 4, h = bh & 15;
  const int t = threadIdx.x;
  const int wave = t >> 6, lane = t & 63, lo = lane & 15, hi = lane >> 4;
  __shared__ ushort_t Qs[64*64];       // [q][d], chunk-swizzled
  __shared__ ushort_t Ks[64*64];       // [j][d], chunk-swizzled
  __shared__ ushort_t Vt[64][72];      // [d][j], padded
  __shared__ ushort_t Ps[4][16][72];   // per-wave P stripe [q][j], padded

  const int count = cnt[b];

  // stage Q tile (gload_lds, source chunks pre-swizzled: c = c' ^ (r&7))
  #pragma unroll
  for (int p = 0; p < 2; ++p){
    int r = p*32 + wave*8 + (lane >> 3);
    int c = (lane & 7) ^ (r & 7);
    const ushort_t* gp = qb + (size_t)(b*64 + r)*1024 + h*64 + c*8;
    char* lp = (char*)Qs + p*4096 + wave*1024;
    GLOAD16(gp, lp);
  }

  f32x4 oacc[4] = {};
  float m[4], l[4];
  #pragma unroll
  for (int rr = 0; rr < 4; ++rr){ m[rr] = -__builtin_inff(); l[rr] = 0.f; }

  const int ntiles = (count + 63) >> 6;
  for (int tt = 0; tt < ntiles; ++tt){
    __syncthreads();   // prev tile fully consumed; Q ready at tt==0
    // stage K tile
    #pragma unroll
    for (int p = 0; p < 2; ++p){
      int r = p*32 + wave*8 + (lane >> 3);
      int c = (lane & 7) ^ (r & 7);
      const ushort_t* gp = kb + (size_t)(b*2048 + tt*64 + r)*1024 + h*64 + c*8;
      char* lp = (char*)Ks + p*4096 + wave*1024;
      GLOAD16(gp, lp);
    }
    // stage V^T (pair-packed writes -> conflict-free b32 stores); zero tail rows
    {
      int jj = (t & 31)*2, c = (t >> 5)*8;
      const ushort_t* g0 = vbuf + (size_t)(b*2048 + tt*64 + jj)*1024 + h*64 + c;
      ushort4v a0 = *(const ushort4v*)(g0);
      ushort4v a1 = *(const ushort4v*)(g0 + 4);
      ushort4v b0 = *(const ushort4v*)(g0 + 1024);
      ushort4v b1 = *(const ushort4v*)(g0 + 1028);
      bool va = (tt*64 + jj)     < count;
      bool vb2 = (tt*64 + jj + 1) < count;
      #pragma unroll
      for (int u = 0; u < 8; ++u){
        ushort_t ea = (u < 4) ? ((ushort_t*)&a0)[u] : ((ushort_t*)&a1)[u-4];
        ushort_t eb = (u < 4) ? ((ushort_t*)&b0)[u] : ((ushort_t*)&b1)[u-4];
        uint32_t word = (va ? (uint32_t)ea : 0u) | ((vb2 ? (uint32_t)eb : 0u) << 16);
        *(uint32_t*)(&Vt[c+u][jj]) = word;
      }
    }
    __syncthreads();   // K (vmcnt) + Vt (lgkm) staged

    // S = Q @ K^T, this wave's 16-query stripe
    f32x4 s[4] = {};
    #pragma unroll
    for (int kk = 0; kk < 2; ++kk){
      int rA = wave*16 + lo;
      short8 aq = *(const short8*)(&Qs[rA*64 + (((kk*4 + hi) ^ (rA & 7))*8)]);
      #pragma unroll
      for (int ni = 0; ni < 4; ++ni){
        int rB = ni*16 + lo;
        short8 bk = *(const short8*)(&Ks[rB*64 + (((kk*4 + hi) ^ (rB & 7))*8)]);
        s[ni] = __builtin_amdgcn_mfma_f32_16x16x32_bf16(aq, bk, s[ni], 0, 0, 0);
      }
    }
    // mask tail columns (also kills NaN from garbage K rows)
    #pragma unroll
    for (int ni = 0; ni < 4; ++ni){
      if (tt*64 + ni*16 + lo >= count){
        s[ni][0] = s[ni][1] = s[ni][2] = s[ni][3] = -__builtin_inff();
      }
    }
    // online softmax (rows spread over regs rr, cols over 16-lane group x 4 frags)
    float p[4][4];
    #pragma unroll
    for (int rr = 0; rr < 4; ++rr){
      float mx = fmaxf(fmaxf(s[0][rr], s[1][rr]), fmaxf(s[2][rr], s[3][rr]));
      #pragma unroll
      for (int d = 1; d < 16; d <<= 1) mx = fmaxf(mx, __shfl_xor(mx, d));
      float mnew = fmaxf(m[rr], mx);
      float sc = __expf(m[rr] - mnew);
      float rsum = 0.f;
      #pragma unroll
      for (int ni = 0; ni < 4; ++ni){
        float pv = __expf(s[ni][rr] - mnew);
        p[ni][rr] = pv;
        rsum += pv;
      }
      #pragma unroll
      for (int d = 1; d < 16; d <<= 1) rsum += __shfl_xor(rsum, d);
      l[rr] = l[rr]*sc + rsum;
      m[rr] = mnew;
      #pragma unroll
      for (int ni = 0; ni < 4; ++ni) oacc[ni][rr] *= sc;
    }
    // P -> LDS (C-layout) then re-read in A-layout for PV
    #pragma unroll
    for (int ni = 0; ni < 4; ++ni)
      #pragma unroll
      for (int rr = 0; rr < 4; ++rr)
        Ps[wave][hi*4+rr][ni*16+lo] = f2bf(p[ni][rr]);
    asm volatile("s_waitcnt lgkmcnt(0)" ::: "memory");
    #pragma unroll
    for (int kk = 0; kk < 2; ++kk){
      short8 pa = *(const short8*)(&Ps[wave][lo][kk*32 + hi*8]);
      #pragma unroll
      for (int ni = 0; ni < 4; ++ni){
        short8 bv = *(const short8*)(&Vt[ni*16 + lo][kk*32 + hi*8]);
        oacc[ni] = __builtin_amdgcn_mfma_f32_16x16x32_bf16(pa, bv, oacc[ni], 0, 0, 0);
      }
    }
  }
  // normalize + write out[b, q, h*64+d]
  #pragma unroll
  for (int rr = 0; rr < 4; ++rr){
    float inv = (l[rr] > 0.f) ? 1.f/l[rr] : 0.f;
    #pragma unroll
    for (int ni = 0; ni < 4; ++ni){
      size_t off = (size_t)(b*64 + wave*16 + hi*4 + rr)*1024 + h*64 + ni*16 + lo;
      outb[off] = f2bf(oacc[ni][rr] * inv);
    }
  }
}

// ---------------------------------------------------------------------------
extern "C" void kernel_launch(void* const* d_in, const int* in_sizes, int n_in,
                              void* d_out, int out_size, void* d_ws, size_t ws_size,
                              hipStream_t stream){
  const float* features = (const float*)d_in[0];
  const int*   mask     = (const int*)  d_in[1];
  const float* latents  = (const float*)d_in[2];
  const float* W_down   = (const float*)d_in[3];
  const float* nin_g    = (const float*)d_in[4];
  const float* nin_b    = (const float*)d_in[5];
  const float* lf_g     = (const float*)d_in[6];
  const float* lf_b     = (const float*)d_in[7];
  const float* ll_g     = (const float*)d_in[8];
  const float* ll_b     = (const float*)d_in[9];
  const float* Wq       = (const float*)d_in[10];
  const float* Wk       = (const float*)d_in[11];
  const float* Wv       = (const float*)d_in[12];
  const float* ffln_g   = (const float*)d_in[13];
  const float* ffln_b   = (const float*)d_in[14];
  const float* ff_w1    = (const float*)d_in[15];
  const float* ff_w2    = (const float*)d_in[16];
  const float* nout_g   = (const float*)d_in[17];
  const float* nout_b   = (const float*)d_in[18];

  char* ws = (char*)d_ws;
  size_t off = 0;
  auto alloc = [&](size_t bytes)->char*{
    char* p = ws + off;
    off += (bytes + 255) & ~(size_t)255;
    return p;
  };
  const size_t SZ_BIG = (size_t)65536*1024*2;
  ushort_t* FHAT = (ushort_t*)alloc(SZ_BIG);
  ushort_t* KBUF = (ushort_t*)alloc(SZ_BIG);   // also FNORM (transient alias)
  ushort_t* VBUF = (ushort_t*)alloc(SZ_BIG);
  ushort_t* WQT  = (ushort_t*)alloc((size_t)1024*1024*2);
  ushort_t* WKT  = (ushort_t*)alloc((size_t)1024*1024*2);
  ushort_t* WVT  = (ushort_t*)alloc((size_t)1024*1024*2);
  ushort_t* W1T  = (ushort_t*)alloc((size_t)2048*1024*2);
  ushort_t* W2T  = (ushort_t*)alloc((size_t)2048*1024*2);
  ushort_t* WDT  = (ushort_t*)alloc((size_t)1024*1024*2);
  float* BD  = (float*)alloc(1024*4);
  float* BQv = (float*)alloc(1024*4);
  float* BKv = (float*)alloc(1024*4);
  float* BVv = (float*)alloc(1024*4);
  float* B1v = (float*)alloc(2048*4);
  float*    X    = (float*)   alloc((size_t)2048*1024*4);
  ushort_t* XHAT = (ushort_t*)alloc((size_t)2048*1024*2);
  ushort_t* QP   = (ushort_t*)alloc((size_t)2048*1024*2);
  ushort_t* OUTB = (ushort_t*)alloc((size_t)2048*1024*2);
  ushort_t* OUTH = (ushort_t*)alloc((size_t)2048*1024*2);
  ushort_t* H1   = (ushort_t*)alloc((size_t)2048*2048*2);
  int* CNT = (int*)alloc(32*4);
  int* IDX = (int*)alloc((size_t)65536*4);
  ushort_t* FNORM = KBUF;
  (void)ws_size; (void)in_sizes; (void)n_in; (void)out_size;

  // ---- setup ----
  k_compact    <<<32,    256, 0, stream>>>(mask, IDX, CNT);
  k_gather_norm<<<65536, 256, 0, stream>>>(features, IDX, CNT, FNORM);
  k_foldT      <<<dim3(16,16), 256, 0, stream>>>(W_down, nin_g, 1.f, WDT, 1024, 1024);
  k_foldBias   <<<32,    256, 0, stream>>>(W_down, nin_b, 1.f, BD, 1024, 1024);
  k_gemm<0,true><<<dim3(8,512), 256, 0, stream>>>(FNORM, WDT, BD, FHAT, 65536, 1024, 1024, CNT);
  k_rownorm_bf16<<<65536, 256, 0, stream>>>(FHAT, FHAT, CNT);
  k_init_x     <<<2048,  256, 0, stream>>>(latents, X);

  const float scale = 0.125f;  // DH^-0.5
  for (int i = 0; i < 6; ++i){
    const float* Wqi = Wq + (size_t)i*1024*1024;
    const float* Wki = Wk + (size_t)i*1024*1024;
    const float* Wvi = Wv + (size_t)i*1024*1024;
    const float* W1i = ff_w1 + (size_t)i*1024*2048;
    const float* W2i = ff_w2 + (size_t)i*2048*1024;

    k_foldT   <<<dim3(16,16), 256, 0, stream>>>(Wqi, ll_g + i*1024, scale, WQT, 1024, 1024);
    k_foldBias<<<32, 256, 0, stream>>>(Wqi, ll_b + i*1024, scale, BQv, 1024, 1024);
    k_foldT   <<<dim3(16,16), 256, 0, stream>>>(Wki, lf_g + i*1024, 1.f, WKT, 1024, 1024);
    k_foldBias<<<32, 256, 0, stream>>>(Wki, lf_b + i*1024, 1.f, BKv, 1024, 1024);
    k_foldT   <<<dim3(16,16), 256, 0, stream>>>(Wvi, lf_g + i*1024, 1.f, WVT, 1024, 1024);
    k_foldBias<<<32, 256, 0, stream>>>(Wvi, lf_b + i*1024, 1.f, BVv, 1024, 1024);
    k_foldT   <<<dim3(32,16), 256, 0, stream>>>(W1i, ffln_g + i*1024, 1.f, W1T, 1024, 2048);
    k_foldBias<<<64, 256, 0, stream>>>(W1i, ffln_b + i*1024, 1.f, B1v, 1024, 2048);
    k_foldT   <<<dim3(16,32), 256, 0, stream>>>(W2i, nullptr, 1.f, W2T, 2048, 1024);

    k_rownorm_f32<<<2048, 256, 0, stream>>>(X, XHAT);
    k_gemm<0,false><<<dim3(8,16),  256, 0, stream>>>(XHAT, WQT, BQv, QP, 2048, 1024, 1024, nullptr);
    k_gemm<0,true> <<<dim3(8,512), 256, 0, stream>>>(FHAT, WKT, BKv, KBUF, 65536, 1024, 1024, CNT);
    k_gemm<0,true> <<<dim3(8,512), 256, 0, stream>>>(FHAT, WVT, BVv, VBUF, 65536, 1024, 1024, CNT);
    k_attn<<<512, 256, 0, stream>>>(QP, KBUF, VBUF, CNT, OUTB);
    k_rownorm_bf16<<<2048, 256, 0, stream>>>(OUTB, OUTH, nullptr);
    k_gemm<1,false><<<dim3(16,16), 256, 0, stream>>>(OUTH, W1T, B1v, H1, 2048, 2048, 1024, nullptr);
    k_gemm<2,false><<<dim3(8,16),  256, 0, stream>>>(H1, W2T, nullptr, X, 2048, 1024, 2048, nullptr);
  }
  k_final_ln<<<2048, 256, 0, stream>>>(X, nout_g, nout_b, (float*)d_out);
}